// Round 2
// baseline (493.330 us; speedup 1.0000x reference)
//
#include <hip/hip_runtime.h>

// ---------------------------------------------------------------------------
// RelGraphConv x3 + action mask, MI355X (gfx950) — round 10
// R9 post-mortem: removing 3 dispatch boundaries gave -1.9 us -> boundaries
// are ~0.7 us, not the bottleneck. Our kernels are ALL below the 42.5 us
// top-5 cutoff (fills own the table) -> zero counter visibility. This round:
// ONE persistent mega-kernel (512 blocks x 512 thr, guaranteed 2 blocks/CU)
// with hand-rolled grid spin barriers (R9's proven fence+atomic pattern) and
// atomic work-queues for load balance. 2 dispatches total. The mega kernel
// WILL exceed the display cutoff -> we finally see our own counters.
//   Discriminates: kernels-slow (dur drops to ~130) vs harness-floor (flat).
// ---------------------------------------------------------------------------

#define STRIDE 64    // bucket capacity; P(deg>=64) astronomically small
#define BINCAP 2560  // records per bin; mean 2048, sigma~45 -> 11 sigma margin

typedef unsigned short ushortT;
typedef __attribute__((ext_vector_type(8))) short short8;   // 8 bf16 (4 VGPRs)
typedef __attribute__((ext_vector_type(4))) float f32x4;    // MFMA C/D

__device__ inline ushortT f2bf(float f) {
    union { float f; unsigned u; } v; v.f = f;
    unsigned r = v.u + 0x7FFFu + ((v.u >> 16) & 1u);   // RNE
    return (ushortT)(r >> 16);
}
__device__ inline float bf2f(ushortT h) {
    union { unsigned u; float f; } v; v.u = ((unsigned)h) << 16;
    return v.f;
}

__device__ inline void atomicMinF(float* addr, float v) {
    if (v >= 0.f) atomicMin((int*)addr, __float_as_int(v));
    else          atomicMax((unsigned int*)addr, __float_as_uint(v));
}

// Grid barrier: release fence + arrive, spin on device-scope atomic reads,
// acquire fence. Only t0 spins; rest of block parked at __syncthreads.
// Pattern proven in-harness by R9's a3m_mask (196-block spin barrier passed).
__device__ inline void gbar(int* bar, int target) {
    __syncthreads();
    if (threadIdx.x == 0) {
        __threadfence();                 // release: publish this XCD's L2
        atomicAdd(bar, 1);
        while (atomicAdd(bar, 0) < target) __builtin_amdgcn_s_sleep(8);
        __threadfence();                 // acquire: invalidate stale L2
    }
    __syncthreads();
}

// ---- K0: weight pack + bincnt/minval/bar/wq init ---------------------------
__global__ __launch_bounds__(256) void pack_init_kernel(
    const float* __restrict__ W1, const float* __restrict__ loop1,
    const float* __restrict__ W2, const float* __restrict__ loop2,
    ushortT* __restrict__ BP1, ushortT* __restrict__ BP2,
    int* __restrict__ bincnt, float* __restrict__ minval,
    int* __restrict__ bar, int* __restrict__ wq, int NBINS) {
    int g = (int)blockIdx.x * 256 + (int)threadIdx.x;  // 0..4607
    if (g < NBINS) bincnt[g] = 0;
    if (g == 0) { *(int*)minval = 0x7f7f7f7f; bar[0] = 0; wq[0] = 0; wq[1] = 0; }
    if (g < 3072) {
        // layer 1: 12 ct x 4 ks x 64 lanes
        int l = g & 63, ks = (g >> 6) & 3, ct = g >> 8;
        int c = ct * 16 + (l & 15);
        int mat = c >> 6, cc = c & 63;
        int kbase = ks * 32 + (l >> 4) * 8;
        ushortT* dstp = BP1 + (size_t)g * 8;
#pragma unroll
        for (int j = 0; j < 8; ++j) {
            int k = kbase + j;
            float v = (mat < 2) ? W1[((size_t)mat * 128 + k) * 64 + cc]
                                : loop1[(size_t)k * 64 + cc];
            dstp[j] = f2bf(v);
        }
    } else {
        // layer 2: 12 ct x 2 ks x 64 lanes
        int s = g - 3072;
        int l = s & 63, ks = (s >> 6) & 1, ct = s >> 7;
        int c = ct * 16 + (l & 15);
        int mat = c >> 6, cc = c & 63;
        int kbase = ks * 32 + (l >> 4) * 8;
        ushortT* dstp = BP2 + (size_t)s * 8;
#pragma unroll
        for (int j = 0; j < 8; ++j) {
            int k = kbase + j;
            float v = (mat < 2) ? W2[((size_t)mat * 64 + k) * 64 + cc]
                                : loop2[(size_t)k * 64 + cc];
            dstp[j] = f2bf(v);
        }
    }
}

// ---- MEGA: everything else, 512 blocks x 512 threads, 4 grid barriers ------
__global__ __launch_bounds__(512, 4) void mega_kernel(
    const float* __restrict__ x, const ushortT* __restrict__ BP1,
    const ushortT* __restrict__ BP2,
    const float* __restrict__ b1, const float* __restrict__ b2,
    const int* __restrict__ src, const int* __restrict__ dst,
    const int* __restrict__ et,
    int* __restrict__ bincnt, int2* __restrict__ binbuf,
    ushortT* __restrict__ hrelb, ushortT* __restrict__ H1b,
    ushortT* __restrict__ hrel2b, ushortT* __restrict__ H2b,
    int* __restrict__ eidx, int* __restrict__ cnt,
    const float* __restrict__ W3, const float* __restrict__ loop3,
    const float* __restrict__ b3,
    float* __restrict__ hrel3, float* __restrict__ H3,
    const int* __restrict__ cs, const int* __restrict__ ms,
    float* __restrict__ minval, int* __restrict__ bar, int* __restrict__ wq,
    float* __restrict__ out,
    int N, int E, int NBINS, int NBA, int NU1, int NU2) {
    // LDS overlay: phase1 needs 12.3 KB, phase2 needs 25.9 KB
    __shared__ __align__(16) char smemraw[25856];
    __shared__ int uS;
    __shared__ float gmS;

    const int t = (int)threadIdx.x;
    const int w = t >> 6, lane = t & 63;
    const int NB = (int)gridDim.x;

    // ======== phase 1: edge binning | gemm1 (dynamic work queue) ===========
    {
        int* hist = (int*)smemraw;                  // [512]
        int* gb   = hist + 512;                     // [512]
        ushortT* rnk = (ushortT*)(gb + 512);        // [4096]
        for (;;) {
            if (t == 0) uS = atomicAdd(&wq[0], 1);
            __syncthreads();
            const int u = uS;
            __syncthreads();
            if (u >= NU1) break;
            if (u < NBA) {
                // ---- bin 4096 edges -----------------------------------------
                for (int i = t; i < NBINS; i += 512) hist[i] = 0;
                __syncthreads();
                const int base = u * 4096;
#pragma unroll
                for (int i = 0; i < 8; ++i) {
                    int e = base + t + i * 512;
                    if (e < E) {
                        int bb = dst[e] >> 7;
                        rnk[t + i * 512] = (ushortT)atomicAdd(&hist[bb], 1);
                    }
                }
                __syncthreads();
                for (int i = t; i < NBINS; i += 512) {
                    int h = hist[i];
                    gb[i] = h ? atomicAdd(&bincnt[i], h) : 0;
                }
                __syncthreads();
#pragma unroll
                for (int i = 0; i < 8; ++i) {
                    int e = base + t + i * 512;
                    if (e < E) {
                        int dd = dst[e];
                        int bb = dd >> 7;
                        int v = et[e] * N + src[e];
                        int pos = gb[bb] + (int)rnk[t + i * 512];
                        if (pos < BINCAP)
                            binbuf[(size_t)bb * BINCAP + pos] = make_int2(dd, v);
                    }
                }
            } else {
                // ---- gemm1 (MFMA): 8 waves x 16 nodes, K=128, no LDS -------
                const int u2 = u - NBA;
                const int rowbase = (u2 * 8 + w) * 16;
                const int m = lane & 15, quad = lane >> 4;
                const int nclamp = min(rowbase + m, N - 1);

                short8 a[4];
                const float* xp = x + (size_t)nclamp * 128 + quad * 8;
#pragma unroll
                for (int ks = 0; ks < 4; ++ks) {
                    float4 g0 = *(const float4*)(xp + ks * 32);
                    float4 g1 = *(const float4*)(xp + ks * 32 + 4);
                    a[ks][0] = (short)f2bf(g0.x); a[ks][1] = (short)f2bf(g0.y);
                    a[ks][2] = (short)f2bf(g0.z); a[ks][3] = (short)f2bf(g0.w);
                    a[ks][4] = (short)f2bf(g1.x); a[ks][5] = (short)f2bf(g1.y);
                    a[ks][6] = (short)f2bf(g1.z); a[ks][7] = (short)f2bf(g1.w);
                }
                f32x4 acc[12];
#pragma unroll
                for (int ct = 0; ct < 12; ++ct) acc[ct] = (f32x4){0.f, 0.f, 0.f, 0.f};
#pragma unroll
                for (int ks = 0; ks < 4; ++ks) {
#pragma unroll
                    for (int ct = 0; ct < 12; ++ct) {
                        short8 b = *(const short8*)&BP1[((size_t)(ct * 4 + ks) * 64 + lane) * 8];
                        acc[ct] = __builtin_amdgcn_mfma_f32_16x16x32_bf16(a[ks], b, acc[ct], 0, 0, 0);
                    }
                }
                const int node0 = rowbase + quad * 4;
#pragma unroll
                for (int ct = 0; ct < 12; ++ct) {
                    int c = ct * 16 + m;
                    int mat = c >> 6, cc = c & 63;
                    float bias = (mat == 2) ? b1[cc] : 0.f;
#pragma unroll
                    for (int j = 0; j < 4; ++j) {
                        int n = node0 + j;
                        if (n < N) {
                            float v = acc[ct][j] + bias;
                            if (mat < 2) hrelb[((size_t)mat * N + n) * 64 + cc] = f2bf(v);
                            else         H1b[(size_t)n * 64 + cc] = f2bf(v);
                        }
                    }
                }
            }
        }
    }
    gbar(bar, NB);

    // ======== phase 2: bin scatter + agg1 + gemm2 (64 nodes per unit) ======
    {
        int* lcnt = (int*)smemraw;                  // [64]
        int* lidx = lcnt + 64;                      // [64][STRIDE] = 16 KB
        ushortT* Hs = (ushortT*)(lidx + 64 * STRIDE);  // [64][72] bf16
        for (;;) {
            if (t == 0) uS = atomicAdd(&wq[1], 1);
            __syncthreads();
            const int u = uS;
            __syncthreads();
            if (u >= NU2) break;
            const int nodeBase = u * 64;
            const int bin = u >> 1;
            if (t < 64) lcnt[t] = 0;
            __syncthreads();
            // ---- scatter our 64 nodes' edges into LDS rows -----------------
            const int cb = min(bincnt[bin], BINCAP);
            const int2* buf = binbuf + (size_t)bin * BINCAP;
            for (int i = t; i < cb; i += 512) {
                int2 rec = buf[i];
                int local = rec.x - nodeBase;
                if ((unsigned)local < 64u) {
                    int r = atomicAdd(&lcnt[local], 1);
                    if (r < STRIDE) {
                        lidx[local * STRIDE + r] = rec.y;
                        eidx[(size_t)rec.x * STRIDE + r] = rec.y;  // for P3/P4
                    }
                }
            }
            __syncthreads();
            if (t < 64) {
                int c = min(lcnt[t], STRIDE);
                lcnt[t] = c;
                int node = nodeBase + t;
                if (node < N) cnt[node] = c;
            }
            __syncthreads();
            // ---- aggregate 8 nodes per wave, lane = channel ----------------
            for (int i = 0; i < 8; ++i) {
                int local = w * 8 + i;
                int node = nodeBase + local;
                if (node >= N) { Hs[local * 72 + lane] = 0; continue; }
                int deg = lcnt[local];
                float acc = bf2f(H1b[(size_t)node * 64 + lane]);
                int j = 0;
                for (; j + 7 < deg; j += 8) {
                    float v[8];
#pragma unroll
                    for (int q = 0; q < 8; ++q) {
                        int id = lidx[local * STRIDE + j + q];
                        v[q] = bf2f(hrelb[(size_t)id * 64 + lane]);
                    }
                    acc += ((v[0] + v[1]) + (v[2] + v[3])) + ((v[4] + v[5]) + (v[6] + v[7]));
                }
                for (; j < deg; ++j)
                    acc += bf2f(hrelb[(size_t)lidx[local * STRIDE + j] * 64 + lane]);
                Hs[local * 72 + lane] = f2bf(fmaxf(acc, 0.f));
            }
            __syncthreads();
            // ---- gemm2: 8 waves = 4 row-tiles x 2 col-halves, K=64 ---------
            {
                const int rt = w & 3, h = w >> 2;
                const int m = lane & 15, quad = lane >> 4;
                short8 a[2];
#pragma unroll
                for (int ks = 0; ks < 2; ++ks)
                    a[ks] = *(const short8*)&Hs[(rt * 16 + m) * 72 + quad * 8 + ks * 32];
                f32x4 acc[6];
#pragma unroll
                for (int c6 = 0; c6 < 6; ++c6) acc[c6] = (f32x4){0.f, 0.f, 0.f, 0.f};
#pragma unroll
                for (int ks = 0; ks < 2; ++ks) {
#pragma unroll
                    for (int c6 = 0; c6 < 6; ++c6) {
                        int ct = h * 6 + c6;
                        short8 b = *(const short8*)&BP2[((size_t)(ct * 2 + ks) * 64 + lane) * 8];
                        acc[c6] = __builtin_amdgcn_mfma_f32_16x16x32_bf16(a[ks], b, acc[c6], 0, 0, 0);
                    }
                }
                const int node0 = nodeBase + rt * 16 + quad * 4;
#pragma unroll
                for (int c6 = 0; c6 < 6; ++c6) {
                    int ct = h * 6 + c6;
                    int c = ct * 16 + m;
                    int mat = c >> 6, cc = c & 63;
                    float bias = (mat == 2) ? b2[cc] : 0.f;
#pragma unroll
                    for (int j = 0; j < 4; ++j) {
                        int n = node0 + j;
                        if (n < N) {
                            float v = acc[c6][j] + bias;
                            if (mat < 2) hrel2b[((size_t)mat * N + n) * 64 + cc] = f2bf(v);
                            else         H2b[(size_t)n * 64 + cc] = f2bf(v);
                        }
                    }
                }
            }
        }
    }
    gbar(bar, NB * 2);

    // ======== phase 3: agg(layer2) + gemm(layer3, out=2), wave-stride ======
    for (int node = (int)blockIdx.x * 8 + w; node < N; node += NB * 8) {
        int deg = cnt[node];
        int my = (lane < deg) ? eidx[(size_t)node * STRIDE + lane] : 0;
        float acc = bf2f(H2b[(size_t)node * 64 + lane]);
        int j = 0;
        for (; j + 7 < deg; j += 8) {
            int id[8];
            float v[8];
#pragma unroll
            for (int q = 0; q < 8; ++q) id[q] = __shfl(my, j + q, 64);
#pragma unroll
            for (int q = 0; q < 8; ++q) v[q] = bf2f(hrel2b[(size_t)id[q] * 64 + lane]);
            acc += ((v[0] + v[1]) + (v[2] + v[3])) + ((v[4] + v[5]) + (v[6] + v[7]));
        }
        for (; j < deg; ++j)
            acc += bf2f(hrel2b[(size_t)__shfl(my, j, 64) * 64 + lane]);
        float xk = fmaxf(acc, 0.f);  // relu(layer-2 out), lane = k
        float p[6];
        p[0] = xk * W3[lane * 2 + 0];
        p[1] = xk * W3[lane * 2 + 1];
        p[2] = xk * W3[(64 + lane) * 2 + 0];
        p[3] = xk * W3[(64 + lane) * 2 + 1];
        p[4] = xk * loop3[lane * 2 + 0];
        p[5] = xk * loop3[lane * 2 + 1];
#pragma unroll
        for (int mm = 32; mm >= 1; mm >>= 1) {
#pragma unroll
            for (int q = 0; q < 6; ++q) p[q] += __shfl_xor(p[q], mm, 64);
        }
        if (lane == 0) {
            hrel3[(size_t)node * 2 + 0] = p[0];
            hrel3[(size_t)node * 2 + 1] = p[1];
            hrel3[((size_t)N + node) * 2 + 0] = p[2];
            hrel3[((size_t)N + node) * 2 + 1] = p[3];
            H3[(size_t)node * 2 + 0] = p[4] + b3[0];
            H3[(size_t)node * 2 + 1] = p[5] + b3[1];
        }
    }
    gbar(bar, NB * 3);

    // ======== phase 4: layer-3 agg + global min + mask =====================
    const int n = (int)blockIdx.x * 512 + t;
    float a0 = 0.f, a1 = 0.f;
    float v = 3.4e38f;
    if (n < N) {
        a0 = H3[n * 2 + 0]; a1 = H3[n * 2 + 1];
        int deg = cnt[n];
        const int* row = &eidx[(size_t)n * STRIDE];
        int j = 0;
        for (; j + 3 < deg; j += 4) {
            int i0 = row[j], i1 = row[j + 1], i2 = row[j + 2], i3 = row[j + 3];
            float2 q0 = *(const float2*)&hrel3[(size_t)i0 * 2];
            float2 q1 = *(const float2*)&hrel3[(size_t)i1 * 2];
            float2 q2 = *(const float2*)&hrel3[(size_t)i2 * 2];
            float2 q3 = *(const float2*)&hrel3[(size_t)i3 * 2];
            a0 += (q0.x + q1.x) + (q2.x + q3.x);
            a1 += (q0.y + q1.y) + (q2.y + q3.y);
        }
        for (; j < deg; ++j) {
            float2 q = *(const float2*)&hrel3[(size_t)row[j] * 2];
            a0 += q.x; a1 += q.y;
        }
        v = fminf(a0, a1);       // h.min() over FINAL h, before masking
    }
#pragma unroll
    for (int mm = 32; mm >= 1; mm >>= 1) v = fminf(v, __shfl_xor(v, mm, 64));
    {
        float* s = (float*)smemraw;
        __syncthreads();
        if (lane == 0) s[w] = v;
        __syncthreads();
        if (t == 0) {
            float bm = s[0];
#pragma unroll
            for (int k = 1; k < 8; ++k) bm = fminf(bm, s[k]);
            atomicMinF(minval, bm);
        }
    }
    gbar(bar, NB * 4);
    if (t == 0) gmS = atomicAdd(minval, 0.0f);   // device-coherent read
    __syncthreads();
    if (n < N) {
        float mn = gmS - 1.0f;
        bool up = cs[n] >= ms[n] - 1;
        bool lo = cs[n] == 0;
        out[n * 2 + 0] = up ? mn : a0;
        out[n * 2 + 1] = lo ? mn : a1;
    }
}

// ---------------------------------------------------------------------------
extern "C" void kernel_launch(void* const* d_in, const int* in_sizes, int n_in,
                              void* d_out, int out_size, void* d_ws, size_t ws_size,
                              hipStream_t stream) {
    const float* x     = (const float*)d_in[0];
    const int* src     = (const int*)d_in[1];
    const int* dst     = (const int*)d_in[2];
    const int* etypes  = (const int*)d_in[3];
    const int* cellsz  = (const int*)d_in[4];
    const int* maxsz   = (const int*)d_in[5];
    const float* W1    = (const float*)d_in[6];
    const float* loop1 = (const float*)d_in[7];
    const float* b1    = (const float*)d_in[8];
    const float* W2    = (const float*)d_in[9];
    const float* loop2 = (const float*)d_in[10];
    const float* b2    = (const float*)d_in[11];
    const float* W3    = (const float*)d_in[12];
    const float* loop3 = (const float*)d_in[13];
    const float* b3    = (const float*)d_in[14];
    float* out = (float*)d_out;

    const int N = in_sizes[0] / 128;  // 50000
    const int E = in_sizes[1];        // 800000

    char* p = (char*)d_ws;
    auto alloc = [&](size_t bytes) -> void* {
        void* r = (void*)p;
        p += ((bytes + 255) / 256) * 256;
        return r;
    };
    ushortT* hrelb  = (ushortT*)alloc((size_t)2 * N * 64 * 2);  // 12.8 MB bf16
    ushortT* H1b    = (ushortT*)alloc((size_t)N * 64 * 2);      //  6.4 MB bf16
    ushortT* hrel2b = (ushortT*)alloc((size_t)2 * N * 64 * 2);  // 12.8 MB bf16
    ushortT* H2b    = (ushortT*)alloc((size_t)N * 64 * 2);      //  6.4 MB bf16
    float* hrel3    = (float*)alloc((size_t)2 * N * 2 * 4);
    float* H3       = (float*)alloc((size_t)N * 2 * 4);
    int* cnt        = (int*)alloc((size_t)N * 4);
    int* eidx       = (int*)alloc((size_t)N * STRIDE * 4);      // 12.8 MB
    ushortT* BP1    = (ushortT*)alloc((size_t)3072 * 8 * 2);    // 48 KB frag-packed
    ushortT* BP2    = (ushortT*)alloc((size_t)1536 * 8 * 2);    // 24 KB
    float* minval   = (float*)alloc(4);
    int* bar        = (int*)alloc(4);                           // own 256B line
    int* wq         = (int*)alloc(8);                           // own 256B line

    const int NBINS = (N + 127) >> 7;                           // 391
    int* bincnt     = (int*)alloc((size_t)NBINS * 4);
    int2* binbuf    = (int2*)alloc((size_t)NBINS * BINCAP * 8); // 8.0 MB
    (void)ws_size; (void)n_in; (void)out_size;

    const int NBA = (E + 4095) / 4096;       // 196 binning units
    const int NT1 = (N + 127) / 128;         // 391 gemm1 units (128 nodes)
    const int NU1 = NBA + NT1;               // phase-1 work queue size
    const int NU2 = (N + 63) / 64;           // 782 phase-2 units (64 nodes)

    // K0: weight pack + all scalar init (bar/wq must be fresh every replay)
    pack_init_kernel<<<18, 256, 0, stream>>>(
        W1, loop1, W2, loop2, BP1, BP2, bincnt, minval, bar, wq, NBINS);

    // MEGA: phases 1-4 with internal grid barriers.
    // 512 blocks x 512 thr = exactly 2 blocks/CU on 256 CUs; co-residency
    // guaranteed by __launch_bounds__(512,4) (VGPR<=128) + 25.9 KB LDS.
    mega_kernel<<<512, 512, 0, stream>>>(
        x, BP1, BP2, b1, b2, src, dst, etypes, bincnt, binbuf,
        hrelb, H1b, hrel2b, H2b, eidx, cnt,
        W3, loop3, b3, hrel3, H3, cellsz, maxsz,
        minval, bar, wq, out,
        N, E, NBINS, NBA, NU1, NU2);
}

// Round 3
// 360.657 us; speedup vs baseline: 1.3679x; 1.3679x over previous
//
#include <hip/hip_runtime.h>

// ---------------------------------------------------------------------------
// RelGraphConv x3 + action mask, MI355X (gfx950) — round 11
// R10 post-mortem: mega-kernel (16 waves/CU) = 420 us, VALUBusy 6.9%,
// MfmaUtil 0.35%, HBM 8%, traffic 266 MB/iter -> pipeline is LATENCY-bound
// on random 128B gathers (2 x 102 MB edge gathers missing per-XCD L2).
// Occupancy is the currency; mega halved it -> 2.3x regression. Revert to R9
// split structure and:
//   * readlane scalar-broadcast gather addressing (SGPR base + invariant
//     lane*2 voffset) in AG2-agg and tail-agg inner loops — kills
//     ds_bpermute + per-edge 64-bit VALU address math on the critical path.
//   * fuse k3+agg3min+mask into tail_kernel: 2048 blocks x 256,
//     __launch_bounds__(256,8) guarantees co-residency; hierarchical
//     2-level barrier (8 group lines, read-only __hip_atomic_load polling).
//     Also makes the biggest kernel visible above the 43us fill cutoff.
// 4 dispatches: pack_init -> k1 (binning || gemm1) -> ag2 -> tail.
// ---------------------------------------------------------------------------

#define STRIDE 64    // bucket capacity; P(deg>=64) astronomically small
#define BINCAP 2560  // records per bin; mean 2048, sigma~45 -> 11 sigma margin
#define TAILNB 2048  // tail grid: 8 blocks/CU x 256 CU, co-resident by bounds

typedef unsigned short ushortT;
typedef __attribute__((ext_vector_type(8))) short short8;   // 8 bf16 (4 VGPRs)
typedef __attribute__((ext_vector_type(4))) float f32x4;    // MFMA C/D

__device__ inline ushortT f2bf(float f) {
    union { float f; unsigned u; } v; v.f = f;
    unsigned r = v.u + 0x7FFFu + ((v.u >> 16) & 1u);   // RNE
    return (ushortT)(r >> 16);
}
__device__ inline float bf2f(ushortT h) {
    union { unsigned u; float f; } v; v.u = ((unsigned)h) << 16;
    return v.f;
}

__device__ inline void atomicMinF(float* addr, float v) {
    if (v >= 0.f) atomicMin((int*)addr, __float_as_int(v));
    else          atomicMax((unsigned int*)addr, __float_as_uint(v));
}

// Hierarchical grid barrier for TAILNB=2048 blocks (8 groups x 256 blocks).
// Arrival: 256 RMWs per group line (parallel across groups), leader bumps
// global. Poll: read-only agent-scope load (no RMW convoy, unlike R10).
// Counters spaced 64 ints (256 B) apart; zeroed by K0 every iteration.
__device__ inline void gbar2(int* ctr, int b) {
    __syncthreads();
    if (threadIdx.x == 0) {
        __threadfence();                          // release our writes
        const int g = (int)blockIdx.x >> 8;       // 0..7
        int* grp  = ctr + (size_t)(b * 9 + g) * 64;
        int* glob = ctr + (size_t)(b * 9 + 8) * 64;
        if (atomicAdd(grp, 1) == 255) atomicAdd(glob, 1);
        while (__hip_atomic_load(glob, __ATOMIC_RELAXED, __HIP_MEMORY_SCOPE_AGENT) < 8)
            __builtin_amdgcn_s_sleep(4);
        __threadfence();                          // acquire others' writes
    }
    __syncthreads();
}

// ---- K0: weight pack + bincnt/minval/barctr init ---------------------------
__global__ __launch_bounds__(256) void pack_init_kernel(
    const float* __restrict__ W1, const float* __restrict__ loop1,
    const float* __restrict__ W2, const float* __restrict__ loop2,
    ushortT* __restrict__ BP1, ushortT* __restrict__ BP2,
    int* __restrict__ bincnt, float* __restrict__ minval,
    int* __restrict__ barctr, int NBINS) {
    int g = (int)blockIdx.x * 256 + (int)threadIdx.x;  // 0..4607
    if (g < NBINS) bincnt[g] = 0;
    if (g < 1152) barctr[g] = 0;                       // 2 barriers x 9 slots x 64
    if (g == 0) *(int*)minval = 0x7f7f7f7f;            // 3.39e38
    if (g < 3072) {
        // layer 1: 12 ct x 4 ks x 64 lanes
        int l = g & 63, ks = (g >> 6) & 3, ct = g >> 8;
        int c = ct * 16 + (l & 15);
        int mat = c >> 6, cc = c & 63;
        int kbase = ks * 32 + (l >> 4) * 8;
        ushortT* dstp = BP1 + (size_t)g * 8;
#pragma unroll
        for (int j = 0; j < 8; ++j) {
            int k = kbase + j;
            float v = (mat < 2) ? W1[((size_t)mat * 128 + k) * 64 + cc]
                                : loop1[(size_t)k * 64 + cc];
            dstp[j] = f2bf(v);
        }
    } else {
        // layer 2: 12 ct x 2 ks x 64 lanes
        int s = g - 3072;
        int l = s & 63, ks = (s >> 6) & 1, ct = s >> 7;
        int c = ct * 16 + (l & 15);
        int mat = c >> 6, cc = c & 63;
        int kbase = ks * 32 + (l >> 4) * 8;
        ushortT* dstp = BP2 + (size_t)s * 8;
#pragma unroll
        for (int j = 0; j < 8; ++j) {
            int k = kbase + j;
            float v = (mat < 2) ? W2[((size_t)mat * 64 + k) * 64 + cc]
                                : loop2[(size_t)k * 64 + cc];
            dstp[j] = f2bf(v);
        }
    }
}

// ---- K1: phaseA-binning [0,NBA) | gemm1 [NBA, NBA+NTILES) ------------------
__global__ __launch_bounds__(256) void k1_kernel(
    const float* __restrict__ x, const ushortT* __restrict__ BP1,
    const float* __restrict__ b1,
    ushortT* __restrict__ hrelb, ushortT* __restrict__ H1b,
    const int* __restrict__ src, const int* __restrict__ dst,
    const int* __restrict__ et, int* __restrict__ bincnt, int2* __restrict__ binbuf,
    int N, int E, int NBINS, int NBA) {
    __shared__ int hist[512];
    __shared__ int gbase[512];
    __shared__ ushortT rnk[4096];

    const int t = (int)threadIdx.x;

    if ((int)blockIdx.x < NBA) {
        // ---- phase A: bin 4096 edges ---------------------------------------
        for (int i = t; i < NBINS; i += 256) hist[i] = 0;
        __syncthreads();
        const int base = (int)blockIdx.x * 4096;
#pragma unroll
        for (int i = 0; i < 16; ++i) {
            int e = base + t + i * 256;
            if (e < E) {
                int bb = dst[e] >> 7;
                rnk[t + i * 256] = (ushortT)atomicAdd(&hist[bb], 1);
            }
        }
        __syncthreads();
        for (int i = t; i < NBINS; i += 256) {
            int h = hist[i];
            gbase[i] = h ? atomicAdd(&bincnt[i], h) : 0;
        }
        __syncthreads();
#pragma unroll
        for (int i = 0; i < 16; ++i) {
            int e = base + t + i * 256;
            if (e < E) {
                int dd = dst[e];
                int bb = dd >> 7;
                int v = et[e] * N + src[e];
                int pos = gbase[bb] + (int)rnk[t + i * 256];
                if (pos < BINCAP)
                    binbuf[(size_t)bb * BINCAP + pos] = make_int2(dd, v);
            }
        }
        return;
    }
    // ---- gemm1 (MFMA): wave = 16 nodes x 192 cols, K=128, no LDS use -------
    const int w = t >> 6, lane = t & 63;
    const int rowbase = (((int)blockIdx.x - NBA) * 4 + w) * 16;
    const int m = lane & 15, quad = lane >> 4;
    const int nclamp = min(rowbase + m, N - 1);

    short8 a[4];
    const float* xp = x + (size_t)nclamp * 128 + quad * 8;
#pragma unroll
    for (int ks = 0; ks < 4; ++ks) {
        float4 g0 = *(const float4*)(xp + ks * 32);
        float4 g1 = *(const float4*)(xp + ks * 32 + 4);
        a[ks][0] = (short)f2bf(g0.x); a[ks][1] = (short)f2bf(g0.y);
        a[ks][2] = (short)f2bf(g0.z); a[ks][3] = (short)f2bf(g0.w);
        a[ks][4] = (short)f2bf(g1.x); a[ks][5] = (short)f2bf(g1.y);
        a[ks][6] = (short)f2bf(g1.z); a[ks][7] = (short)f2bf(g1.w);
    }

    f32x4 acc[12];
#pragma unroll
    for (int ct = 0; ct < 12; ++ct) acc[ct] = (f32x4){0.f, 0.f, 0.f, 0.f};

#pragma unroll
    for (int ks = 0; ks < 4; ++ks) {
#pragma unroll
        for (int ct = 0; ct < 12; ++ct) {
            short8 b = *(const short8*)&BP1[((size_t)(ct * 4 + ks) * 64 + lane) * 8];
            acc[ct] = __builtin_amdgcn_mfma_f32_16x16x32_bf16(a[ks], b, acc[ct], 0, 0, 0);
        }
    }

    const int node0 = rowbase + quad * 4;
#pragma unroll
    for (int ct = 0; ct < 12; ++ct) {
        int c = ct * 16 + m;
        int mat = c >> 6, cc = c & 63;
        float bias = (mat == 2) ? b1[cc] : 0.f;
#pragma unroll
        for (int j = 0; j < 4; ++j) {
            int n = node0 + j;
            if (n < N) {
                float v = acc[ct][j] + bias;
                if (mat < 2) hrelb[((size_t)mat * N + n) * 64 + cc] = f2bf(v);
                else         H1b[(size_t)n * 64 + cc] = f2bf(v);
            }
        }
    }
}

// ---- AG2: fused phaseB (half-bin) + agg(layer1) + gemm2 (MFMA) -------------
__global__ __launch_bounds__(512, 4) void ag2_kernel(
    const ushortT* __restrict__ hrelb, const ushortT* __restrict__ H1b,
    const ushortT* __restrict__ BP2, const float* __restrict__ b2,
    const int* __restrict__ bincnt, const int2* __restrict__ binbuf,
    int* __restrict__ eidx, int* __restrict__ cnt,
    ushortT* __restrict__ hrel2b, ushortT* __restrict__ H2b, int N) {
    __shared__ int lcnt[64];
    __shared__ int lidx[64][STRIDE];                       // 16 KB
    __shared__ __align__(16) ushortT Hs[64][72];           // 9.2 KB

    const int t = (int)threadIdx.x;
    const int B = (int)blockIdx.x;
    const int nodeBase = B * 64;
    const int bin = B >> 1;

    if (t < 64) lcnt[t] = 0;
    __syncthreads();

    // ---- phase 0: filter bin records for our 64 nodes ----------------------
    const int cb = min(bincnt[bin], BINCAP);
    const int2* buf = binbuf + (size_t)bin * BINCAP;
    for (int i = t; i < cb; i += 512) {
        int2 rec = buf[i];
        int local = rec.x - nodeBase;
        if ((unsigned)local < 64u) {
            int r = atomicAdd(&lcnt[local], 1);
            if (r < STRIDE) {
                lidx[local][r] = rec.y;
                eidx[(size_t)rec.x * STRIDE + r] = rec.y;   // for tail phases
            }
        }
    }
    __syncthreads();
    if (t < 64) {
        int c = min(lcnt[t], STRIDE);
        lcnt[t] = c;
        int node = nodeBase + t;
        if (node < N) cnt[node] = c;
    }
    __syncthreads();

    const int w = t >> 6, lane = t & 63;

    // ---- phase 1: aggregate 8 nodes per wave, lane = channel ---------------
    // readlane scalar-broadcast: id -> SGPR, address = SGPR base + lane*2.
    for (int i = 0; i < 8; ++i) {
        int local = w * 8 + i;
        int node = nodeBase + local;
        if (node >= N) { Hs[local][lane] = 0; continue; }
        int deg = lcnt[local];
        int my = lidx[local][lane];                        // lane's edge id
        float acc = bf2f(H1b[(size_t)node * 64 + lane]);   // self-loop + bias
        int j = 0;
        for (; j + 7 < deg; j += 8) {
            float v[8];
#pragma unroll
            for (int q = 0; q < 8; ++q) {
                int id = __builtin_amdgcn_readlane(my, j + q);   // uniform SGPR
                v[q] = bf2f(hrelb[(size_t)id * 64 + lane]);
            }
            acc += ((v[0] + v[1]) + (v[2] + v[3])) + ((v[4] + v[5]) + (v[6] + v[7]));
        }
        for (; j < deg; ++j) {
            int id = __builtin_amdgcn_readlane(my, j);
            acc += bf2f(hrelb[(size_t)id * 64 + lane]);
        }
        Hs[local][lane] = f2bf(fmaxf(acc, 0.f));           // relu, LDS only
    }
    __syncthreads();

    // ---- phase 2: gemm2, wave = 16 rows x 96 cols, K=64 --------------------
    const int rt = w & 3, h = w >> 2;
    const int m = lane & 15, quad = lane >> 4;
    short8 a[2];
#pragma unroll
    for (int ks = 0; ks < 2; ++ks)
        a[ks] = *(const short8*)&Hs[rt * 16 + m][quad * 8 + ks * 32];

    f32x4 acc[6];
#pragma unroll
    for (int c6 = 0; c6 < 6; ++c6) acc[c6] = (f32x4){0.f, 0.f, 0.f, 0.f};

#pragma unroll
    for (int ks = 0; ks < 2; ++ks) {
#pragma unroll
        for (int c6 = 0; c6 < 6; ++c6) {
            int ct = h * 6 + c6;
            short8 b = *(const short8*)&BP2[((size_t)(ct * 2 + ks) * 64 + lane) * 8];
            acc[c6] = __builtin_amdgcn_mfma_f32_16x16x32_bf16(a[ks], b, acc[c6], 0, 0, 0);
        }
    }

    const int node0 = nodeBase + rt * 16 + quad * 4;
#pragma unroll
    for (int c6 = 0; c6 < 6; ++c6) {
        int ct = h * 6 + c6;
        int c = ct * 16 + m;
        int mat = c >> 6, cc = c & 63;
        float bias = (mat == 2) ? b2[cc] : 0.f;
#pragma unroll
        for (int j = 0; j < 4; ++j) {
            int n = node0 + j;
            if (n < N) {
                float v = acc[c6][j] + bias;
                if (mat < 2) hrel2b[((size_t)mat * N + n) * 64 + cc] = f2bf(v);
                else         H2b[(size_t)n * 64 + cc] = f2bf(v);
            }
        }
    }
}

// ---- TAIL: agg(l2)+gemm(l3) -> gbar -> agg(l3)+min -> gbar -> mask ---------
// 2048 blocks x 256 thr; __launch_bounds__(256,8) caps VGPR at 64 -> 8
// blocks/CU -> all 2048 co-resident on 256 CUs. Grid-stride phase A keeps
// full 32 waves/CU occupancy for the latency-bound gather.
__global__ __launch_bounds__(256, 8) void tail_kernel(
    const ushortT* __restrict__ hrel2b, const ushortT* __restrict__ H2b,
    const int* __restrict__ eidx, const int* __restrict__ cnt,
    const float* __restrict__ W3, const float* __restrict__ loop3,
    const float* __restrict__ b3,
    const int* __restrict__ cs, const int* __restrict__ ms,
    float* __restrict__ hrel3, float* __restrict__ H3,
    float* __restrict__ minval, int* __restrict__ barctr,
    float* __restrict__ out, int N) {
    const int t = (int)threadIdx.x;
    const int w = t >> 6, lane = t & 63;

    // ---- phase A: agg(layer2) + layer-3 mini-gemm, wave per node -----------
    const float w3a = W3[lane * 2 + 0], w3b = W3[lane * 2 + 1];
    const float w3c = W3[(64 + lane) * 2 + 0], w3d = W3[(64 + lane) * 2 + 1];
    const float l3a = loop3[lane * 2 + 0], l3b = loop3[lane * 2 + 1];
    for (int node = (int)blockIdx.x * 4 + w; node < N; node += TAILNB * 4) {
        int deg = cnt[node];
        int my = eidx[(size_t)node * STRIDE + lane];
        float acc = bf2f(H2b[(size_t)node * 64 + lane]);
        int j = 0;
        for (; j + 7 < deg; j += 8) {
            float v[8];
#pragma unroll
            for (int q = 0; q < 8; ++q) {
                int id = __builtin_amdgcn_readlane(my, j + q);   // uniform SGPR
                v[q] = bf2f(hrel2b[(size_t)id * 64 + lane]);
            }
            acc += ((v[0] + v[1]) + (v[2] + v[3])) + ((v[4] + v[5]) + (v[6] + v[7]));
        }
        for (; j < deg; ++j) {
            int id = __builtin_amdgcn_readlane(my, j);
            acc += bf2f(hrel2b[(size_t)id * 64 + lane]);
        }
        float xk = fmaxf(acc, 0.f);  // relu(layer-2 out), lane = k
        float p0 = xk * w3a, p1 = xk * w3b, p2 = xk * w3c;
        float p3 = xk * w3d, p4 = xk * l3a, p5 = xk * l3b;
#pragma unroll
        for (int mm = 32; mm >= 1; mm >>= 1) {
            p0 += __shfl_xor(p0, mm, 64);
            p1 += __shfl_xor(p1, mm, 64);
            p2 += __shfl_xor(p2, mm, 64);
            p3 += __shfl_xor(p3, mm, 64);
            p4 += __shfl_xor(p4, mm, 64);
            p5 += __shfl_xor(p5, mm, 64);
        }
        if (lane == 0) {
            hrel3[(size_t)node * 2 + 0] = p0;
            hrel3[(size_t)node * 2 + 1] = p1;
            hrel3[((size_t)N + node) * 2 + 0] = p2;
            hrel3[((size_t)N + node) * 2 + 1] = p3;
            H3[(size_t)node * 2 + 0] = p4 + b3[0];
            H3[(size_t)node * 2 + 1] = p5 + b3[1];
        }
    }
    gbar2(barctr, 0);

    // ---- phase B: layer-3 aggregation + global min -------------------------
    const int n = (int)blockIdx.x * 256 + t;
    float a0 = 0.f, a1 = 0.f;
    float v = 3.4e38f;
    if (n < N) {
        a0 = H3[n * 2 + 0]; a1 = H3[n * 2 + 1];
        int deg = cnt[n];
        const int* row = &eidx[(size_t)n * STRIDE];
        int j = 0;
        for (; j + 3 < deg; j += 4) {
            int i0 = row[j], i1 = row[j + 1], i2 = row[j + 2], i3 = row[j + 3];
            float2 q0 = *(const float2*)&hrel3[(size_t)i0 * 2];
            float2 q1 = *(const float2*)&hrel3[(size_t)i1 * 2];
            float2 q2 = *(const float2*)&hrel3[(size_t)i2 * 2];
            float2 q3 = *(const float2*)&hrel3[(size_t)i3 * 2];
            a0 += (q0.x + q1.x) + (q2.x + q3.x);
            a1 += (q0.y + q1.y) + (q2.y + q3.y);
        }
        for (; j < deg; ++j) {
            float2 q = *(const float2*)&hrel3[(size_t)row[j] * 2];
            a0 += q.x; a1 += q.y;
        }
        v = fminf(a0, a1);       // h.min() over FINAL h, before masking
    }
#pragma unroll
    for (int mm = 32; mm >= 1; mm >>= 1) v = fminf(v, __shfl_xor(v, mm, 64));
    {
        __shared__ float s[4];
        if (lane == 0) s[w] = v;
        __syncthreads();
        if (t == 0)
            atomicMinF(minval, fminf(fminf(s[0], s[1]), fminf(s[2], s[3])));
    }
    gbar2(barctr, 1);

    // ---- phase C: mask from registers --------------------------------------
    __shared__ float gmS;
    if (t == 0) gmS = atomicAdd(minval, 0.0f);   // device-coherent read
    __syncthreads();
    if (n < N) {
        float mn = gmS - 1.0f;
        bool up = cs[n] >= ms[n] - 1;
        bool lo = cs[n] == 0;
        out[n * 2 + 0] = up ? mn : a0;
        out[n * 2 + 1] = lo ? mn : a1;
    }
}

// ---------------------------------------------------------------------------
extern "C" void kernel_launch(void* const* d_in, const int* in_sizes, int n_in,
                              void* d_out, int out_size, void* d_ws, size_t ws_size,
                              hipStream_t stream) {
    const float* x     = (const float*)d_in[0];
    const int* src     = (const int*)d_in[1];
    const int* dst     = (const int*)d_in[2];
    const int* etypes  = (const int*)d_in[3];
    const int* cellsz  = (const int*)d_in[4];
    const int* maxsz   = (const int*)d_in[5];
    const float* W1    = (const float*)d_in[6];
    const float* loop1 = (const float*)d_in[7];
    const float* b1    = (const float*)d_in[8];
    const float* W2    = (const float*)d_in[9];
    const float* loop2 = (const float*)d_in[10];
    const float* b2    = (const float*)d_in[11];
    const float* W3    = (const float*)d_in[12];
    const float* loop3 = (const float*)d_in[13];
    const float* b3    = (const float*)d_in[14];
    float* out = (float*)d_out;

    const int N = in_sizes[0] / 128;  // 50000
    const int E = in_sizes[1];        // 800000

    char* p = (char*)d_ws;
    auto alloc = [&](size_t bytes) -> void* {
        void* r = (void*)p;
        p += ((bytes + 255) / 256) * 256;
        return r;
    };
    ushortT* hrelb  = (ushortT*)alloc((size_t)2 * N * 64 * 2);  // 12.8 MB bf16
    ushortT* H1b    = (ushortT*)alloc((size_t)N * 64 * 2);      //  6.4 MB bf16
    ushortT* hrel2b = (ushortT*)alloc((size_t)2 * N * 64 * 2);  // 12.8 MB bf16
    ushortT* H2b    = (ushortT*)alloc((size_t)N * 64 * 2);      //  6.4 MB bf16
    float* hrel3    = (float*)alloc((size_t)2 * N * 2 * 4);
    float* H3       = (float*)alloc((size_t)N * 2 * 4);
    int* cnt        = (int*)alloc((size_t)N * 4);
    int* eidx       = (int*)alloc((size_t)N * STRIDE * 4);      // 12.8 MB
    ushortT* BP1    = (ushortT*)alloc((size_t)3072 * 8 * 2);    // 48 KB frag-packed
    ushortT* BP2    = (ushortT*)alloc((size_t)1536 * 8 * 2);    // 24 KB
    float* minval   = (float*)alloc(4);
    int* barctr     = (int*)alloc((size_t)1152 * 4);            // 2 barriers x 9 x 64

    const int NBINS = (N + 127) >> 7;                           // 391
    int* bincnt     = (int*)alloc((size_t)NBINS * 4);
    int2* binbuf    = (int2*)alloc((size_t)NBINS * BINCAP * 8); // 8.0 MB
    (void)ws_size; (void)n_in; (void)out_size;

    const int NBA    = (E + 4095) / 4096;    // 196 phase-A blocks
    const int NTILES = (N + 63) / 64;        // 782
    const int NB_AG  = (N + 63) / 64;        // 782 fused blocks (64 nodes each)

    // K0: weight pack + bincnt/minval/barctr init (producer ordering)
    pack_init_kernel<<<18, 256, 0, stream>>>(
        W1, loop1, W2, loop2, BP1, BP2, bincnt, minval, barctr, NBINS);

    // K1: phase-A binning || layer-1 MFMA GEMM (independent halves)
    k1_kernel<<<NBA + NTILES, 256, 0, stream>>>(
        x, BP1, b1, hrelb, H1b,
        src, dst, etypes, bincnt, binbuf, N, E, NBINS, NBA);

    // AG2: fused phaseB + agg(layer1) + gemm2
    ag2_kernel<<<NB_AG, 512, 0, stream>>>(
        hrelb, H1b, BP2, b2, bincnt, binbuf, eidx, cnt, hrel2b, H2b, N);

    // TAIL: agg(l2)+gemm(l3) -> barrier -> agg(l3)+min -> barrier -> mask
    tail_kernel<<<TAILNB, 256, 0, stream>>>(
        hrel2b, H2b, eidx, cnt, W3, loop3, b3, cellsz, maxsz,
        hrel3, H3, minval, barctr, out, N);
}

// Round 4
// 232.117 us; speedup vs baseline: 2.1253x; 1.5538x over previous
//
#include <hip/hip_runtime.h>

// ---------------------------------------------------------------------------
// RelGraphConv x3 + action mask, MI355X (gfx950) — round 12
// R10/R11 post-mortem: persistent-kernel structures (grid-stride + spin
// barriers with >500 pollers) cost 140-270 us vs the same phases as split
// dispatches (~0.7 us/boundary). Occupancy is NOT the lever (48% and 89%
// both slow). Empirical law: dispatch boundaries are the cheapest grid
// barrier on this pipeline. Revert to the R9 skeleton (218.5 us) exactly,
// ONE technique change: gather MLP 8 -> 16 outstanding loads by pairing
// nodes with dual accumulators in both gather loops (ag2 phase-1, k3).
// Batch boundaries preserved -> bitwise-identical sums to R9.
// 5 dispatches: pack_init -> k1 (binning || gemm1) -> ag2 -> k3 -> a3m_mask.
// ---------------------------------------------------------------------------

#define STRIDE 64    // bucket capacity; P(deg>=64) astronomically small
#define BINCAP 2560  // records per bin; mean 2048, sigma~45 -> 11 sigma margin

typedef unsigned short ushortT;
typedef __attribute__((ext_vector_type(8))) short short8;   // 8 bf16 (4 VGPRs)
typedef __attribute__((ext_vector_type(4))) float f32x4;    // MFMA C/D

__device__ inline ushortT f2bf(float f) {
    union { float f; unsigned u; } v; v.f = f;
    unsigned r = v.u + 0x7FFFu + ((v.u >> 16) & 1u);   // RNE
    return (ushortT)(r >> 16);
}
__device__ inline float bf2f(ushortT h) {
    union { unsigned u; float f; } v; v.u = ((unsigned)h) << 16;
    return v.f;
}

__device__ inline void atomicMinF(float* addr, float v) {
    if (v >= 0.f) atomicMin((int*)addr, __float_as_int(v));
    else          atomicMax((unsigned int*)addr, __float_as_uint(v));
}

// ---- K0: weight pack + bincnt/minval/done init -----------------------------
__global__ __launch_bounds__(256) void pack_init_kernel(
    const float* __restrict__ W1, const float* __restrict__ loop1,
    const float* __restrict__ W2, const float* __restrict__ loop2,
    ushortT* __restrict__ BP1, ushortT* __restrict__ BP2,
    int* __restrict__ bincnt, float* __restrict__ minval,
    int* __restrict__ done, int NBINS) {
    int g = (int)blockIdx.x * 256 + (int)threadIdx.x;  // 0..4607
    if (g < NBINS) bincnt[g] = 0;
    if (g == 0) { *(int*)minval = 0x7f7f7f7f; *done = 0; }
    if (g < 3072) {
        // layer 1: 12 ct x 4 ks x 64 lanes
        int l = g & 63, ks = (g >> 6) & 3, ct = g >> 8;
        int c = ct * 16 + (l & 15);
        int mat = c >> 6, cc = c & 63;
        int kbase = ks * 32 + (l >> 4) * 8;
        ushortT* dstp = BP1 + (size_t)g * 8;
#pragma unroll
        for (int j = 0; j < 8; ++j) {
            int k = kbase + j;
            float v = (mat < 2) ? W1[((size_t)mat * 128 + k) * 64 + cc]
                                : loop1[(size_t)k * 64 + cc];
            dstp[j] = f2bf(v);
        }
    } else {
        // layer 2: 12 ct x 2 ks x 64 lanes
        int s = g - 3072;
        int l = s & 63, ks = (s >> 6) & 1, ct = s >> 7;
        int c = ct * 16 + (l & 15);
        int mat = c >> 6, cc = c & 63;
        int kbase = ks * 32 + (l >> 4) * 8;
        ushortT* dstp = BP2 + (size_t)s * 8;
#pragma unroll
        for (int j = 0; j < 8; ++j) {
            int k = kbase + j;
            float v = (mat < 2) ? W2[((size_t)mat * 64 + k) * 64 + cc]
                                : loop2[(size_t)k * 64 + cc];
            dstp[j] = f2bf(v);
        }
    }
}

// ---- K1: phaseA-binning [0,NBA) | gemm1 [NBA, NBA+NTILES) ------------------
__global__ __launch_bounds__(256) void k1_kernel(
    const float* __restrict__ x, const ushortT* __restrict__ BP1,
    const float* __restrict__ b1,
    ushortT* __restrict__ hrelb, ushortT* __restrict__ H1b,
    const int* __restrict__ src, const int* __restrict__ dst,
    const int* __restrict__ et, int* __restrict__ bincnt, int2* __restrict__ binbuf,
    int N, int E, int NBINS, int NBA) {
    __shared__ int hist[512];
    __shared__ int gbase[512];
    __shared__ ushortT rnk[4096];

    const int t = (int)threadIdx.x;

    if ((int)blockIdx.x < NBA) {
        // ---- phase A: bin 4096 edges ---------------------------------------
        for (int i = t; i < NBINS; i += 256) hist[i] = 0;
        __syncthreads();
        const int base = (int)blockIdx.x * 4096;
#pragma unroll
        for (int i = 0; i < 16; ++i) {
            int e = base + t + i * 256;
            if (e < E) {
                int bb = dst[e] >> 7;
                rnk[t + i * 256] = (ushortT)atomicAdd(&hist[bb], 1);
            }
        }
        __syncthreads();
        for (int i = t; i < NBINS; i += 256) {
            int h = hist[i];
            gbase[i] = h ? atomicAdd(&bincnt[i], h) : 0;
        }
        __syncthreads();
#pragma unroll
        for (int i = 0; i < 16; ++i) {
            int e = base + t + i * 256;
            if (e < E) {
                int dd = dst[e];
                int bb = dd >> 7;
                int v = et[e] * N + src[e];
                int pos = gbase[bb] + (int)rnk[t + i * 256];
                if (pos < BINCAP)
                    binbuf[(size_t)bb * BINCAP + pos] = make_int2(dd, v);
            }
        }
        return;
    }
    // ---- gemm1 (MFMA): wave = 16 nodes x 192 cols, K=128, no LDS use -------
    const int w = t >> 6, lane = t & 63;
    const int rowbase = (((int)blockIdx.x - NBA) * 4 + w) * 16;
    const int m = lane & 15, quad = lane >> 4;
    const int nclamp = min(rowbase + m, N - 1);

    short8 a[4];
    const float* xp = x + (size_t)nclamp * 128 + quad * 8;
#pragma unroll
    for (int ks = 0; ks < 4; ++ks) {
        float4 g0 = *(const float4*)(xp + ks * 32);
        float4 g1 = *(const float4*)(xp + ks * 32 + 4);
        a[ks][0] = (short)f2bf(g0.x); a[ks][1] = (short)f2bf(g0.y);
        a[ks][2] = (short)f2bf(g0.z); a[ks][3] = (short)f2bf(g0.w);
        a[ks][4] = (short)f2bf(g1.x); a[ks][5] = (short)f2bf(g1.y);
        a[ks][6] = (short)f2bf(g1.z); a[ks][7] = (short)f2bf(g1.w);
    }

    f32x4 acc[12];
#pragma unroll
    for (int ct = 0; ct < 12; ++ct) acc[ct] = (f32x4){0.f, 0.f, 0.f, 0.f};

#pragma unroll
    for (int ks = 0; ks < 4; ++ks) {
#pragma unroll
        for (int ct = 0; ct < 12; ++ct) {
            short8 b = *(const short8*)&BP1[((size_t)(ct * 4 + ks) * 64 + lane) * 8];
            acc[ct] = __builtin_amdgcn_mfma_f32_16x16x32_bf16(a[ks], b, acc[ct], 0, 0, 0);
        }
    }

    const int node0 = rowbase + quad * 4;
#pragma unroll
    for (int ct = 0; ct < 12; ++ct) {
        int c = ct * 16 + m;
        int mat = c >> 6, cc = c & 63;
        float bias = (mat == 2) ? b1[cc] : 0.f;
#pragma unroll
        for (int j = 0; j < 4; ++j) {
            int n = node0 + j;
            if (n < N) {
                float v = acc[ct][j] + bias;
                if (mat < 2) hrelb[((size_t)mat * N + n) * 64 + cc] = f2bf(v);
                else         H1b[(size_t)n * 64 + cc] = f2bf(v);
            }
        }
    }
}

// ---- AG2: fused phaseB (half-bin) + agg(layer1) + gemm2 (MFMA) -------------
// phase1 change vs R9: nodes processed in PAIRS with dual accumulators ->
// 16 outstanding gather loads per wave (was 8). Batch grouping per node is
// unchanged (8-wide from j=0, scalar drain) -> bitwise-identical sums.
__global__ __launch_bounds__(512, 4) void ag2_kernel(
    const ushortT* __restrict__ hrelb, const ushortT* __restrict__ H1b,
    const ushortT* __restrict__ BP2, const float* __restrict__ b2,
    const int* __restrict__ bincnt, const int2* __restrict__ binbuf,
    int* __restrict__ eidx, int* __restrict__ cnt,
    ushortT* __restrict__ hrel2b, ushortT* __restrict__ H2b, int N) {
    __shared__ int lcnt[64];
    __shared__ int lidx[64][STRIDE];                       // 16 KB
    __shared__ __align__(16) ushortT Hs[64][72];           // 9.2 KB

    const int t = (int)threadIdx.x;
    const int B = (int)blockIdx.x;
    const int nodeBase = B * 64;
    const int bin = B >> 1;

    if (t < 64) lcnt[t] = 0;
    __syncthreads();

    // ---- phase 0: filter bin records for our 64 nodes ----------------------
    const int cb = min(bincnt[bin], BINCAP);
    const int2* buf = binbuf + (size_t)bin * BINCAP;
    for (int i = t; i < cb; i += 512) {
        int2 rec = buf[i];
        int local = rec.x - nodeBase;
        if ((unsigned)local < 64u) {
            int r = atomicAdd(&lcnt[local], 1);
            if (r < STRIDE) {
                lidx[local][r] = rec.y;
                eidx[(size_t)rec.x * STRIDE + r] = rec.y;   // for k3 / a3m
            }
        }
    }
    __syncthreads();
    if (t < 64) {
        int c = min(lcnt[t], STRIDE);
        lcnt[t] = c;
        int node = nodeBase + t;
        if (node < N) cnt[node] = c;
    }
    __syncthreads();

    const int w = t >> 6, lane = t & 63;

    // ---- phase 1: aggregate 8 nodes per wave as 4 pairs, lane = channel ----
    for (int i = 0; i < 8; i += 2) {
        const int lA = w * 8 + i, lB = lA + 1;
        const int nA = nodeBase + lA, nB = nodeBase + lB;
        const bool okA = nA < N, okB = nB < N;
        const int dA = okA ? lcnt[lA] : 0;
        const int dB = okB ? lcnt[lB] : 0;
        float accA = okA ? bf2f(H1b[(size_t)nA * 64 + lane]) : 0.f;
        float accB = okB ? bf2f(H1b[(size_t)nB * 64 + lane]) : 0.f;
        const int dmin = min(dA, dB);
        int j = 0;
        for (; j + 7 < dmin; j += 8) {          // 16 loads in flight
            float va[8], vb[8];
#pragma unroll
            for (int q = 0; q < 8; ++q) {
                int idA = lidx[lA][j + q];      // LDS broadcast, free
                int idB = lidx[lB][j + q];
                va[q] = bf2f(hrelb[(size_t)idA * 64 + lane]);
                vb[q] = bf2f(hrelb[(size_t)idB * 64 + lane]);
            }
            accA += ((va[0] + va[1]) + (va[2] + va[3])) + ((va[4] + va[5]) + (va[6] + va[7]));
            accB += ((vb[0] + vb[1]) + (vb[2] + vb[3])) + ((vb[4] + vb[5]) + (vb[6] + vb[7]));
        }
        int ja = j;
        for (; ja + 7 < dA; ja += 8) {          // drain A 8-wide
            float va[8];
#pragma unroll
            for (int q = 0; q < 8; ++q)
                va[q] = bf2f(hrelb[(size_t)lidx[lA][ja + q] * 64 + lane]);
            accA += ((va[0] + va[1]) + (va[2] + va[3])) + ((va[4] + va[5]) + (va[6] + va[7]));
        }
        for (; ja < dA; ++ja)
            accA += bf2f(hrelb[(size_t)lidx[lA][ja] * 64 + lane]);
        int jb = j;
        for (; jb + 7 < dB; jb += 8) {          // drain B 8-wide
            float vb[8];
#pragma unroll
            for (int q = 0; q < 8; ++q)
                vb[q] = bf2f(hrelb[(size_t)lidx[lB][jb + q] * 64 + lane]);
            accB += ((vb[0] + vb[1]) + (vb[2] + vb[3])) + ((vb[4] + vb[5]) + (vb[6] + vb[7]));
        }
        for (; jb < dB; ++jb)
            accB += bf2f(hrelb[(size_t)lidx[lB][jb] * 64 + lane]);
        Hs[lA][lane] = f2bf(fmaxf(accA, 0.f));  // relu, LDS only
        Hs[lB][lane] = f2bf(fmaxf(accB, 0.f));
    }
    __syncthreads();

    // ---- phase 2: gemm2, wave = 16 rows x 96 cols, K=64 --------------------
    const int rt = w & 3, h = w >> 2;
    const int m = lane & 15, quad = lane >> 4;
    short8 a[2];
#pragma unroll
    for (int ks = 0; ks < 2; ++ks)
        a[ks] = *(const short8*)&Hs[rt * 16 + m][quad * 8 + ks * 32];

    f32x4 acc[6];
#pragma unroll
    for (int c6 = 0; c6 < 6; ++c6) acc[c6] = (f32x4){0.f, 0.f, 0.f, 0.f};

#pragma unroll
    for (int ks = 0; ks < 2; ++ks) {
#pragma unroll
        for (int c6 = 0; c6 < 6; ++c6) {
            int ct = h * 6 + c6;
            short8 b = *(const short8*)&BP2[((size_t)(ct * 2 + ks) * 64 + lane) * 8];
            acc[c6] = __builtin_amdgcn_mfma_f32_16x16x32_bf16(a[ks], b, acc[c6], 0, 0, 0);
        }
    }

    const int node0 = nodeBase + rt * 16 + quad * 4;
#pragma unroll
    for (int c6 = 0; c6 < 6; ++c6) {
        int ct = h * 6 + c6;
        int c = ct * 16 + m;
        int mat = c >> 6, cc = c & 63;
        float bias = (mat == 2) ? b2[cc] : 0.f;
#pragma unroll
        for (int j = 0; j < 4; ++j) {
            int n = node0 + j;
            if (n < N) {
                float v = acc[c6][j] + bias;
                if (mat < 2) hrel2b[((size_t)mat * N + n) * 64 + cc] = f2bf(v);
                else         H2b[(size_t)n * 64 + cc] = f2bf(v);
            }
        }
    }
}

// ---- K3: fused agg(layer2) + gemm(layer3, out=2), wave per NODE-PAIR -------
// Change vs R9: each wave handles 2 nodes with interleaved gathers -> 16
// outstanding loads (was 8). Batch grouping per node unchanged.
__global__ void k3_kernel(const ushortT* __restrict__ hrel2b, const ushortT* __restrict__ H2b,
                          const int* __restrict__ eidx, const int* __restrict__ cnt,
                          const float* __restrict__ W3, const float* __restrict__ loop3,
                          const float* __restrict__ b3,
                          float* __restrict__ hrel3, float* __restrict__ H3, int N) {
    const int t = (int)threadIdx.x;
    const int w = t >> 6, lane = t & 63;
    const int nA = (int)blockIdx.x * 8 + w * 2;
    const int nB = nA + 1;
    if (nA >= N) return;
    const bool okB = nB < N;

    const int dA = cnt[nA];
    const int dB = okB ? cnt[nB] : 0;
    int myA = (lane < dA) ? eidx[(size_t)nA * STRIDE + lane] : 0;
    int myB = (okB && lane < dB) ? eidx[(size_t)nB * STRIDE + lane] : 0;
    float accA = bf2f(H2b[(size_t)nA * 64 + lane]);
    float accB = okB ? bf2f(H2b[(size_t)nB * 64 + lane]) : 0.f;

    const int dmin = min(dA, dB);
    int j = 0;
    for (; j + 7 < dmin; j += 8) {              // 16 loads in flight
        int ia[8], ib[8];
        float va[8], vb[8];
#pragma unroll
        for (int q = 0; q < 8; ++q) {
            ia[q] = __shfl(myA, j + q, 64);
            ib[q] = __shfl(myB, j + q, 64);
        }
#pragma unroll
        for (int q = 0; q < 8; ++q) {
            va[q] = bf2f(hrel2b[(size_t)ia[q] * 64 + lane]);
            vb[q] = bf2f(hrel2b[(size_t)ib[q] * 64 + lane]);
        }
        accA += ((va[0] + va[1]) + (va[2] + va[3])) + ((va[4] + va[5]) + (va[6] + va[7]));
        accB += ((vb[0] + vb[1]) + (vb[2] + vb[3])) + ((vb[4] + vb[5]) + (vb[6] + vb[7]));
    }
    int ja = j;
    for (; ja + 7 < dA; ja += 8) {
        int ia[8]; float va[8];
#pragma unroll
        for (int q = 0; q < 8; ++q) ia[q] = __shfl(myA, ja + q, 64);
#pragma unroll
        for (int q = 0; q < 8; ++q) va[q] = bf2f(hrel2b[(size_t)ia[q] * 64 + lane]);
        accA += ((va[0] + va[1]) + (va[2] + va[3])) + ((va[4] + va[5]) + (va[6] + va[7]));
    }
    for (; ja < dA; ++ja)
        accA += bf2f(hrel2b[(size_t)__shfl(myA, ja, 64) * 64 + lane]);
    int jb = j;
    for (; jb + 7 < dB; jb += 8) {
        int ib[8]; float vb[8];
#pragma unroll
        for (int q = 0; q < 8; ++q) ib[q] = __shfl(myB, jb + q, 64);
#pragma unroll
        for (int q = 0; q < 8; ++q) vb[q] = bf2f(hrel2b[(size_t)ib[q] * 64 + lane]);
        accB += ((vb[0] + vb[1]) + (vb[2] + vb[3])) + ((vb[4] + vb[5]) + (vb[6] + vb[7]));
    }
    for (; jb < dB; ++jb)
        accB += bf2f(hrel2b[(size_t)__shfl(myB, jb, 64) * 64 + lane]);

    const float w3a = W3[lane * 2 + 0], w3b = W3[lane * 2 + 1];
    const float w3c = W3[(64 + lane) * 2 + 0], w3d = W3[(64 + lane) * 2 + 1];
    const float l3a = loop3[lane * 2 + 0], l3b = loop3[lane * 2 + 1];

    float xA = fmaxf(accA, 0.f), xB = fmaxf(accB, 0.f);
    float p[12];
    p[0] = xA * w3a;  p[1]  = xA * w3b;  p[2]  = xA * w3c;
    p[3] = xA * w3d;  p[4]  = xA * l3a;  p[5]  = xA * l3b;
    p[6] = xB * w3a;  p[7]  = xB * w3b;  p[8]  = xB * w3c;
    p[9] = xB * w3d;  p[10] = xB * l3a;  p[11] = xB * l3b;
#pragma unroll
    for (int mm = 32; mm >= 1; mm >>= 1) {
#pragma unroll
        for (int q = 0; q < 12; ++q) p[q] += __shfl_xor(p[q], mm, 64);
    }
    if (lane == 0) {
        hrel3[(size_t)nA * 2 + 0] = p[0];
        hrel3[(size_t)nA * 2 + 1] = p[1];
        hrel3[((size_t)N + nA) * 2 + 0] = p[2];
        hrel3[((size_t)N + nA) * 2 + 1] = p[3];
        H3[(size_t)nA * 2 + 0] = p[4] + b3[0];
        H3[(size_t)nA * 2 + 1] = p[5] + b3[1];
        if (okB) {
            hrel3[(size_t)nB * 2 + 0] = p[6];
            hrel3[(size_t)nB * 2 + 1] = p[7];
            hrel3[((size_t)N + nB) * 2 + 0] = p[8];
            hrel3[((size_t)N + nB) * 2 + 1] = p[9];
            H3[(size_t)nB * 2 + 0] = p[10] + b3[0];
            H3[(size_t)nB * 2 + 1] = p[11] + b3[1];
        }
    }
}

// ---- A3M+MASK: layer-3 agg + global min (co-resident spin barrier) + mask --
// 196 blocks — proven-safe poller count (R9). Unchanged from R9.
__global__ __launch_bounds__(256) void a3m_mask_kernel(
    const float* __restrict__ hrel3, const int* __restrict__ eidx,
    const int* __restrict__ cnt, const float* __restrict__ H3,
    const int* __restrict__ cs, const int* __restrict__ ms,
    float* __restrict__ minval, int* __restrict__ done,
    float* __restrict__ out, int N) {
    const int t = (int)threadIdx.x;
    const int n = (int)blockIdx.x * 256 + t;
    float a0 = 0.f, a1 = 0.f;
    float v = 3.4e38f;
    if (n < N) {
        a0 = H3[n * 2 + 0]; a1 = H3[n * 2 + 1];
        int deg = cnt[n];
        const int* row = &eidx[(size_t)n * STRIDE];
        int j = 0;
        for (; j + 3 < deg; j += 4) {
            int i0 = row[j], i1 = row[j + 1], i2 = row[j + 2], i3 = row[j + 3];
            float2 q0 = *(const float2*)&hrel3[(size_t)i0 * 2];
            float2 q1 = *(const float2*)&hrel3[(size_t)i1 * 2];
            float2 q2 = *(const float2*)&hrel3[(size_t)i2 * 2];
            float2 q3 = *(const float2*)&hrel3[(size_t)i3 * 2];
            a0 += (q0.x + q1.x) + (q2.x + q3.x);
            a1 += (q0.y + q1.y) + (q2.y + q3.y);
        }
        for (; j < deg; ++j) {
            float2 q = *(const float2*)&hrel3[(size_t)row[j] * 2];
            a0 += q.x; a1 += q.y;
        }
        v = fminf(a0, a1);       // h.min() over FINAL h, before masking
    }
#pragma unroll
    for (int mm = 32; mm >= 1; mm >>= 1) v = fminf(v, __shfl_xor(v, mm, 64));
    __shared__ float s[4];
    __shared__ float gm;
    if ((t & 63) == 0) s[t >> 6] = v;
    __syncthreads();
    if (t == 0) {
        atomicMinF(minval, fminf(fminf(s[0], s[1]), fminf(s[2], s[3])));
        __threadfence();                        // order minval before done
        atomicAdd(done, 1);
        while (atomicAdd(done, 0) < (int)gridDim.x)  // 196 pollers: proven OK
            __builtin_amdgcn_s_sleep(2);
        gm = atomicAdd(minval, 0.0f);           // atomic read of final min
    }
    __syncthreads();
    if (n < N) {
        float mn = gm - 1.0f;
        bool up = cs[n] >= ms[n] - 1;
        bool lo = cs[n] == 0;
        out[n * 2 + 0] = up ? mn : a0;
        out[n * 2 + 1] = lo ? mn : a1;
    }
}

// ---------------------------------------------------------------------------
extern "C" void kernel_launch(void* const* d_in, const int* in_sizes, int n_in,
                              void* d_out, int out_size, void* d_ws, size_t ws_size,
                              hipStream_t stream) {
    const float* x     = (const float*)d_in[0];
    const int* src     = (const int*)d_in[1];
    const int* dst     = (const int*)d_in[2];
    const int* etypes  = (const int*)d_in[3];
    const int* cellsz  = (const int*)d_in[4];
    const int* maxsz   = (const int*)d_in[5];
    const float* W1    = (const float*)d_in[6];
    const float* loop1 = (const float*)d_in[7];
    const float* b1    = (const float*)d_in[8];
    const float* W2    = (const float*)d_in[9];
    const float* loop2 = (const float*)d_in[10];
    const float* b2    = (const float*)d_in[11];
    const float* W3    = (const float*)d_in[12];
    const float* loop3 = (const float*)d_in[13];
    const float* b3    = (const float*)d_in[14];
    float* out = (float*)d_out;

    const int N = in_sizes[0] / 128;  // 50000
    const int E = in_sizes[1];        // 800000

    char* p = (char*)d_ws;
    auto alloc = [&](size_t bytes) -> void* {
        void* r = (void*)p;
        p += ((bytes + 255) / 256) * 256;
        return r;
    };
    ushortT* hrelb  = (ushortT*)alloc((size_t)2 * N * 64 * 2);  // 12.8 MB bf16
    ushortT* H1b    = (ushortT*)alloc((size_t)N * 64 * 2);      //  6.4 MB bf16
    ushortT* hrel2b = (ushortT*)alloc((size_t)2 * N * 64 * 2);  // 12.8 MB bf16
    ushortT* H2b    = (ushortT*)alloc((size_t)N * 64 * 2);      //  6.4 MB bf16
    float* hrel3    = (float*)alloc((size_t)2 * N * 2 * 4);
    float* H3       = (float*)alloc((size_t)N * 2 * 4);
    int* cnt        = (int*)alloc((size_t)N * 4);
    int* eidx       = (int*)alloc((size_t)N * STRIDE * 4);      // 12.8 MB
    ushortT* BP1    = (ushortT*)alloc((size_t)3072 * 8 * 2);    // 48 KB frag-packed
    ushortT* BP2    = (ushortT*)alloc((size_t)1536 * 8 * 2);    // 24 KB
    float* minval   = (float*)alloc(4);
    int* done       = (int*)alloc(4);                           // own 256B chunk

    const int NBINS = (N + 127) >> 7;                           // 391
    int* bincnt     = (int*)alloc((size_t)NBINS * 4);
    int2* binbuf    = (int2*)alloc((size_t)NBINS * BINCAP * 8); // 8.0 MB
    (void)ws_size; (void)n_in; (void)out_size;

    const int NB_N   = (N + 255) / 256;      // 196
    const int NTILES = (N + 63) / 64;        // 782
    const int NB_K3  = (N + 7) / 8;          // 6250 (2 nodes per wave)
    const int NBA    = (E + 4095) / 4096;    // 196 phase-A blocks
    const int NB_AG  = (N + 63) / 64;        // 782 fused blocks (64 nodes each)

    // K0: weight pack + bincnt/minval/done init (producer ordering)
    pack_init_kernel<<<18, 256, 0, stream>>>(
        W1, loop1, W2, loop2, BP1, BP2, bincnt, minval, done, NBINS);

    // K1: phase-A binning || layer-1 MFMA GEMM (independent halves)
    k1_kernel<<<NBA + NTILES, 256, 0, stream>>>(
        x, BP1, b1, hrelb, H1b,
        src, dst, etypes, bincnt, binbuf, N, E, NBINS, NBA);

    // AG2: fused phaseB + agg(layer1) + gemm2
    ag2_kernel<<<NB_AG, 512, 0, stream>>>(
        hrelb, H1b, BP2, b2, bincnt, binbuf, eidx, cnt, hrel2b, H2b, N);

    // fused agg(layer2) + gemm(layer3), 2 nodes per wave
    k3_kernel<<<NB_K3, 256, 0, stream>>>(hrel2b, H2b, eidx, cnt, W3, loop3, b3,
                                         hrel3, H3, N);

    // fused layer-3 aggregation + global min (spin barrier) + mask
    a3m_mask_kernel<<<NB_N, 256, 0, stream>>>(hrel3, eidx, cnt, H3,
                                              cellsz, maxsz, minval, done, out, N);
}